// Round 7
// baseline (598.689 us; speedup 1.0000x reference)
//
#include <hip/hip_runtime.h>
#include <hip/hip_bf16.h>

#define D_MODEL 768
#define NH 12
#define DK 64
#define RQ 6
#define RK 2
#define RV 2
#define BATCH 8
#define SEQ 4096
#define NPOS (BATCH*SEQ)

typedef _Float16 v8h __attribute__((ext_vector_type(8)));
typedef float v4f __attribute__((ext_vector_type(4)));

// Async global->LDS DMA, 16B per lane. LDS dest is wave-uniform base + lane*16.
#define GLDS16(ldst, gsrc)                                                     \
    __builtin_amdgcn_global_load_lds(                                          \
        (const __attribute__((address_space(1))) void*)(unsigned long long)    \
            (const void*)(gsrc),                                               \
        (__attribute__((address_space(3))) void*)(unsigned int)                \
            (unsigned long long)(void*)(ldst),                                 \
        16, 0, 0)

#define VMCNT(n) asm volatile("s_waitcnt vmcnt(" #n ")" ::: "memory")
#define BAR() do { asm volatile("" ::: "memory");                              \
                   __builtin_amdgcn_s_barrier();                               \
                   asm volatile("" ::: "memory"); } while (0)

// ---------------------------------------------------------------------------
// Repack (fp32 -> fp16): WcatT[n][k] = concat-weights transposed, bcat[n] fp32;
// WoT[n][k] = Wo[k][n]. n in [760,768) zero-padded.
// ---------------------------------------------------------------------------
__global__ __launch_bounds__(256) void repack(
    const float* __restrict__ Waq, const float* __restrict__ baq,
    const float* __restrict__ Wbq, const float* __restrict__ bbq,
    const float* __restrict__ Wak, const float* __restrict__ bak,
    const float* __restrict__ Wbk, const float* __restrict__ bbk,
    const float* __restrict__ Wav, const float* __restrict__ bav,
    const float* __restrict__ Wbv, const float* __restrict__ bbv,
    const float* __restrict__ Wo,
    _Float16* __restrict__ WcatT, _Float16* __restrict__ WoT,
    float* __restrict__ bcat)
{
    const int n = blockIdx.x;   // 0..767
    const int t = threadIdx.x;
    const float* W = nullptr; const float* bsrc = nullptr;
    int cols = 0, col = 0;
    if      (n <  72) { W=Waq; bsrc=baq; cols=72;  col=n;     }
    else if (n < 456) { W=Wbq; bsrc=bbq; cols=384; col=n-72;  }
    else if (n < 480) { W=Wak; bsrc=bak; cols=24;  col=n-456; }
    else if (n < 608) { W=Wbk; bsrc=bbk; cols=128; col=n-480; }
    else if (n < 632) { W=Wav; bsrc=bav; cols=24;  col=n-608; }
    else if (n < 760) { W=Wbv; bsrc=bbv; cols=128; col=n-632; }
    for (int k = t; k < 768; k += 256) {
        WcatT[(size_t)n*768 + k] = W ? (_Float16)W[(size_t)k*cols + col] : (_Float16)0.f;
        WoT[(size_t)n*768 + k]   = (_Float16)Wo[(size_t)k*768 + n];
    }
    if (t == 0) bcat[n] = W ? bsrc[col] : 0.f;
}

// ---------------------------------------------------------------------------
// x fp32 -> fp16, vectorized (2x float4 in, 1x v8h out per iter).
// ---------------------------------------------------------------------------
__global__ __launch_bounds__(256) void convert_x(
    const float4* __restrict__ x, v8h* __restrict__ xh)
{
    const int nth = gridDim.x * 256;
    for (int i = blockIdx.x*256 + threadIdx.x; i < NPOS*96; i += nth) {
        float4 a = x[2*(size_t)i];
        float4 b = x[2*(size_t)i + 1];
        v8h h;
        h[0]=(_Float16)a.x; h[1]=(_Float16)a.y; h[2]=(_Float16)a.z; h[3]=(_Float16)a.w;
        h[4]=(_Float16)b.x; h[5]=(_Float16)b.y; h[6]=(_Float16)b.z; h[7]=(_Float16)b.w;
        xh[i] = h;
    }
}

// ---------------------------------------------------------------------------
// MFMA GEMM, row-panel tiling: block = 64 rows x ALL 768 cols, 8 waves.
// Wave w owns col-panel [w*96, w*96+96): acc 4x6 frags (24 MFMA/K-step).
// Per K-step: stage A 64x32 (4KB, waves 0-3 one 1KB DMA each -> ALL waves
// consume: 192 MFMA per staged A sub-tile, 6x the arithmetic intensity per
// staged byte of the 128x128 tiling) + B 48KB (6 DMA per wave, wave-private
// cols; B is 1.18MB total -> L2-hot for the whole grid). Double-buffered,
// counted per-wave vmcnt (waves 0-3 have 7 loads in flight, 4-7 have 6:
// wave-uniform branch). LDS fragment layouts give 2 lanes/bank per 16-lane
// phase (= conflict-free, same algebra as the R1 zero-conflict layout).
// MODE 0: epilogue bias+rope (P). MODE 1: epilogue bias (Y).
// ---------------------------------------------------------------------------
template<int MODE>
__global__ __launch_bounds__(512, 1) void mfma_gemm(
    const _Float16* __restrict__ A,
    const _Float16* __restrict__ BT,
    const float* __restrict__ bias,
    const float* __restrict__ rope,
    float* __restrict__ C)
{
    const int t = threadIdx.x;          // 0..511
    const int lane = t & 63;
    const int wave = t >> 6;            // 0..7

    // bijective XCD swizzle of the 512-block grid (512 % 8 == 0)
    const int flat = blockIdx.x;
    const int rt = (flat & 7) * 64 + (flat >> 3);   // 0..511
    const int row0 = rt * 64;

    __shared__ v8h Asl[2][256];        // [buf][kc*64 + row]        8 KB
    __shared__ v8h Bsl[2][8][384];     // [buf][wave][kc*96 + col] 96 KB

    v4f acc[4][6];
    #pragma unroll
    for (int i = 0; i < 4; ++i)
        #pragma unroll
        for (int j = 0; j < 6; ++j)
            acc[i][j] = (v4f){0.f, 0.f, 0.f, 0.f};

    const v8h* gA = (const v8h*)A;     // row stride 96 chunks
    const v8h* gB = (const v8h*)BT;

    // A staging (waves 0-3 only): instr = wave; lane l -> row l, kc = wave.
    //   src gA[(row0+l)*96 + ks*4 + wave]; dest Asl[buf][wave*64 + l].
    const size_t gaL = (size_t)(row0 + lane)*96 + wave;

    // B staging (all waves, private col-panel): 6 instrs j; slot = j*64+lane
    //   -> kc = slot/96, col = slot%96.
    //   src gB[(colPan+col)*96 + ks*4 + kc]; dest Bsl[buf][wave][slot].
    const int colPan = wave * 96;
    size_t gbL[6];
    #pragma unroll
    for (int j = 0; j < 6; ++j) {
        int slot = j*64 + lane;
        int kcB  = slot / 96;
        int colB = slot - kcB*96;
        gbL[j] = (size_t)(colPan + colB)*96 + kcB;
    }

    const int q = lane >> 4;   // k-chunk within fragment
    const int m = lane & 15;

#define STAGE(b, ks) do {                                                      \
    _Pragma("unroll")                                                          \
    for (int j_ = 0; j_ < 6; ++j_)                                             \
        GLDS16((char*)&Bsl[b][wave][j_*64] + lane*16, gB + gbL[j_] + (ks)*4);  \
    if (wave < 4)                                                              \
        GLDS16((char*)&Asl[b][wave*64] + lane*16, gA + gaL + (ks)*4);          \
} while (0)

// wait for the PREVIOUS buffer's loads only (this buffer's 6/7 stay in flight)
#define WAITP() do { if (wave < 4) VMCNT(7); else VMCNT(6); } while (0)

// Fragment reads (verified element map):
//   af[mi] = A elem (row=mi*16+m, kc=q)  -> Asl[b][q*64 + mi*16 + m]
//   bf[ni] = B elem (col=ni*16+m, kc=q)  -> Bsl[b][wave][q*96 + ni*16 + m]
// Bank: per 16-lane phase addr step = 16B -> 2 lanes/bank = free.
#define CMP(b) do {                                                            \
    v8h af[4], bf[6];                                                          \
    _Pragma("unroll")                                                          \
    for (int i_ = 0; i_ < 4; ++i_) af[i_] = Asl[b][q*64 + i_*16 + m];          \
    _Pragma("unroll")                                                          \
    for (int i_ = 0; i_ < 6; ++i_) bf[i_] = Bsl[b][wave][q*96 + i_*16 + m];    \
    __builtin_amdgcn_s_setprio(1);                                             \
    _Pragma("unroll")                                                          \
    for (int mi_ = 0; mi_ < 4; ++mi_)                                          \
        _Pragma("unroll")                                                      \
        for (int ni_ = 0; ni_ < 6; ++ni_)                                      \
            acc[mi_][ni_] = __builtin_amdgcn_mfma_f32_16x16x32_f16(            \
                af[mi_], bf[ni_], acc[mi_][ni_], 0, 0, 0);                     \
    __builtin_amdgcn_s_setprio(0);                                             \
} while (0)

    // 24 K-steps (BK=32), dbuf: stage T+1, wait T, barrier, compute T, barrier.
    STAGE(0, 0);
    for (int u = 0; u < 11; ++u) {
        STAGE(1, 2*u + 1); WAITP(); BAR(); CMP(0); BAR();
        STAGE(0, 2*u + 2); WAITP(); BAR(); CMP(1); BAR();
    }
    STAGE(1, 23); WAITP(); BAR(); CMP(0); BAR();
    VMCNT(0);            BAR(); CMP(1);

#undef STAGE
#undef WAITP
#undef CMP

    // Epilogue. C/D layout: col = lane&15, row = (lane>>4)*4 + reg.
    #pragma unroll
    for (int mi = 0; mi < 4; ++mi) {
        #pragma unroll
        for (int i = 0; i < 4; ++i) {
            const int grow = row0 + mi*16 + q*4 + i;
            #pragma unroll
            for (int ni = 0; ni < 6; ++ni) {
                const int gcol = colPan + ni*16 + m;
                float v = acc[mi][ni][i] + bias[gcol];
                if (MODE == 0) {
                    const int s = grow & 4095;
                    if (gcol >= 72 && gcol < 456)
                        v *= rope[s*64 + ((gcol - 72) & 63)];
                    else if (gcol >= 480 && gcol < 608)
                        v *= rope[s*64 + ((gcol - 480) & 63)];
                }
                C[(size_t)grow*768 + gcol] = v;
            }
        }
    }
}

// ---------------------------------------------------------------------------
// Factorized per-position attention (rope already in P). 8 positions per
// 256-thread block. O fp16, layout [b][h][s][d].
// ---------------------------------------------------------------------------
__global__ __launch_bounds__(256) void tpa_attn_f(
    const float* __restrict__ P,
    _Float16* __restrict__ O)
{
    const int t = threadIdx.x;
    const int pos0 = blockIdx.x * 8;

    __shared__ float proj[8][772];   // row pad 768->772: de-bank positions
    __shared__ float Gs[8][12];
    __shared__ float sc[8][160];     // 12 rows x stride 13
    __shared__ float cs[8][24];

    // load 8 P-rows (float4)
    const float4* gp = (const float4*)P;
    for (int i = t; i < 8*192; i += 256) {
        int p = i / 192, c = i - p*192;
        float4 u = gp[(size_t)(pos0 + p)*192 + c];
        proj[p][c*4+0] = u.x; proj[p][c*4+1] = u.y;
        proj[p][c*4+2] = u.z; proj[p][c*4+3] = u.w;
    }
    __syncthreads();

    // Gram matrix: 8 pos x 12 (r,r') pairs
    if (t < 96) {
        int p = t / 12, u = t - (t/12)*12, r = u >> 1, r2 = u & 1;
        const float* bq = &proj[p][72  + r*64];
        const float* bk = &proj[p][480 + r2*64];
        const int ph = (r*8 + r2*16) & 63;   // stagger start to spread banks
        float acc = 0.f;
        for (int i = 0; i < 64; ++i) {
            int d = (i + ph) & 63;
            acc = fmaf(bq[d], bk[d], acc);
        }
        Gs[p][u] = acc * 0.125f;
    }
    __syncthreads();

    // scores: 8 pos x 144 (h,g)
    for (int i = t; i < 8*144; i += 256) {
        int p = i / 144, v = i - p*144, h = v / 12, g = v - (v/12)*12;
        float s = 0.f;
        #pragma unroll
        for (int r = 0; r < RQ; ++r) {
            float mg = fmaf(Gs[p][r*2+1], proj[p][468 + g],
                            Gs[p][r*2+0] * proj[p][456 + g]);
            s = fmaf(proj[p][r*12 + h], mg, s);
        }
        sc[p][h*13 + g] = s;
    }
    __syncthreads();

    // softmax over g: 96 rows
    if (t < 96) {
        int p = t / 12, h = t - (t/12)*12;
        float* row = &sc[p][h*13];
        float mx = -1e30f;
        #pragma unroll
        for (int g = 0; g < NH; ++g) mx = fmaxf(mx, row[g]);
        float sum = 0.f;
        #pragma unroll
        for (int g = 0; g < NH; ++g) { float e = __expf(row[g]-mx); row[g] = e; sum += e; }
        float inv = 1.0f / sum;
        #pragma unroll
        for (int g = 0; g < NH; ++g) row[g] *= inv;
    }
    __syncthreads();

    // c[h,r'] = attn . av^T : 8 pos x 24
    if (t < 192) {
        int p = t / 24, u = t - (t/24)*24, h = u >> 1, r2 = u & 1;
        float acc = 0.f;
        #pragma unroll
        for (int g = 0; g < NH; ++g)
            acc = fmaf(sc[p][h*13+g], proj[p][608 + r2*12 + g], acc);
        cs[p][h*2 + r2] = acc;
    }
    __syncthreads();

    // out: 8 pos x 768, d fastest for coalesced fp16 stores
    for (int i = t; i < 8*768; i += 256) {
        int p = i / 768, j = i - p*768, h = j >> 6, d = j & 63;
        int pos = pos0 + p, b = pos >> 12, s = pos & 4095;
        float val = fmaf(cs[p][h*2+1], proj[p][632 + 64 + d],
                         cs[p][h*2+0] * proj[p][632 + d]);
        O[(((size_t)b*NH + h)*SEQ + s)*DK + d] = (_Float16)val;
    }
}

extern "C" void kernel_launch(void* const* d_in, const int* in_sizes, int n_in,
                              void* d_out, int out_size, void* d_ws, size_t ws_size,
                              hipStream_t stream) {
    const float* x    = (const float*)d_in[0];
    const float* rope = (const float*)d_in[1];
    const float* Waq  = (const float*)d_in[2];
    const float* baq  = (const float*)d_in[3];
    const float* Wbq  = (const float*)d_in[4];
    const float* bbq  = (const float*)d_in[5];
    const float* Wak  = (const float*)d_in[6];
    const float* bak  = (const float*)d_in[7];
    const float* Wbk  = (const float*)d_in[8];
    const float* bbk  = (const float*)d_in[9];
    const float* Wav  = (const float*)d_in[10];
    const float* bav  = (const float*)d_in[11];
    const float* Wbv  = (const float*)d_in[12];
    const float* bbv  = (const float*)d_in[13];
    const float* Wo   = (const float*)d_in[14];
    const float* bo   = (const float*)d_in[15];

    // ws layout (total ~52.7 MB): fp16 weights + fp16 O
    char* ws = (char*)d_ws;
    _Float16* WcatT = (_Float16*)(ws);                 // 1,179,648 B
    _Float16* WoT   = (_Float16*)(ws + 1179648);       // 1,179,648 B
    float*    bcat  = (float*)(ws + 2359296);          // 3,072 B
    _Float16* O     = (_Float16*)(ws + 2363392);       // 50,331,648 B

    // P (fp32, 32768x768) lives in d_out; fully consumed by tpa_attn_f
    // before the final GEMM overwrites d_out.
    float* P = (float*)d_out;

    // Xh (fp16 x, 48 MB) time-shares the O region.
    _Float16* Xh = O;

    repack<<<768, 256, 0, stream>>>(Waq, baq, Wbq, bbq, Wak, bak, Wbk, bbk,
                                    Wav, bav, Wbv, bbv, Wo, WcatT, WoT, bcat);

    convert_x<<<1024, 256, 0, stream>>>((const float4*)x, (v8h*)Xh);

    mfma_gemm<0><<<512, 512, 0, stream>>>(Xh, WcatT, bcat, rope, P);

    tpa_attn_f<<<NPOS/8, 256, 0, stream>>>(P, O);

    mfma_gemm<1><<<512, 512, 0, stream>>>(O, WoT, bo, nullptr, (float*)d_out);
}

// Round 8
// 374.388 us; speedup vs baseline: 1.5991x; 1.5991x over previous
//
#include <hip/hip_runtime.h>
#include <hip/hip_bf16.h>

#define D_MODEL 768
#define NH 12
#define DK 64
#define RQ 6
#define RK 2
#define RV 2
#define BATCH 8
#define SEQ 4096
#define NPOS (BATCH*SEQ)

typedef _Float16 v8h __attribute__((ext_vector_type(8)));
typedef float v4f __attribute__((ext_vector_type(4)));

// Async global->LDS DMA, 16B per lane. LDS dest is wave-uniform base + lane*16.
#define GLDS16(ldst, gsrc)                                                     \
    __builtin_amdgcn_global_load_lds(                                          \
        (const __attribute__((address_space(1))) void*)(unsigned long long)    \
            (const void*)(gsrc),                                               \
        (__attribute__((address_space(3))) void*)(unsigned int)                \
            (unsigned long long)(void*)(ldst),                                 \
        16, 0, 0)

#define VMCNT(n) asm volatile("s_waitcnt vmcnt(" #n ")" ::: "memory")
#define BAR() do { asm volatile("" ::: "memory");                              \
                   __builtin_amdgcn_s_barrier();                               \
                   asm volatile("" ::: "memory"); } while (0)

// ---------------------------------------------------------------------------
// Repack (fp32 -> fp16): WcatT[n][k] = concat-weights transposed, bcat[n] fp32;
// WoT[n][k] = Wo[k][n]. n in [760,768) zero-padded.
// ---------------------------------------------------------------------------
__global__ __launch_bounds__(256) void repack(
    const float* __restrict__ Waq, const float* __restrict__ baq,
    const float* __restrict__ Wbq, const float* __restrict__ bbq,
    const float* __restrict__ Wak, const float* __restrict__ bak,
    const float* __restrict__ Wbk, const float* __restrict__ bbk,
    const float* __restrict__ Wav, const float* __restrict__ bav,
    const float* __restrict__ Wbv, const float* __restrict__ bbv,
    const float* __restrict__ Wo,
    _Float16* __restrict__ WcatT, _Float16* __restrict__ WoT,
    float* __restrict__ bcat)
{
    const int n = blockIdx.x;   // 0..767
    const int t = threadIdx.x;
    const float* W = nullptr; const float* bsrc = nullptr;
    int cols = 0, col = 0;
    if      (n <  72) { W=Waq; bsrc=baq; cols=72;  col=n;     }
    else if (n < 456) { W=Wbq; bsrc=bbq; cols=384; col=n-72;  }
    else if (n < 480) { W=Wak; bsrc=bak; cols=24;  col=n-456; }
    else if (n < 608) { W=Wbk; bsrc=bbk; cols=128; col=n-480; }
    else if (n < 632) { W=Wav; bsrc=bav; cols=24;  col=n-608; }
    else if (n < 760) { W=Wbv; bsrc=bbv; cols=128; col=n-632; }
    for (int k = t; k < 768; k += 256) {
        WcatT[(size_t)n*768 + k] = W ? (_Float16)W[(size_t)k*cols + col] : (_Float16)0.f;
        WoT[(size_t)n*768 + k]   = (_Float16)Wo[(size_t)k*768 + n];
    }
    if (t == 0) bcat[n] = W ? bsrc[col] : 0.f;
}

// ---------------------------------------------------------------------------
// x fp32 -> fp16, vectorized (2x float4 in, 1x v8h out per iter).
// ---------------------------------------------------------------------------
__global__ __launch_bounds__(256) void convert_x(
    const float4* __restrict__ x, v8h* __restrict__ xh)
{
    const int nth = gridDim.x * 256;
    for (int i = blockIdx.x*256 + threadIdx.x; i < NPOS*96; i += nth) {
        float4 a = x[2*(size_t)i];
        float4 b = x[2*(size_t)i + 1];
        v8h h;
        h[0]=(_Float16)a.x; h[1]=(_Float16)a.y; h[2]=(_Float16)a.z; h[3]=(_Float16)a.w;
        h[4]=(_Float16)b.x; h[5]=(_Float16)b.y; h[6]=(_Float16)b.z; h[7]=(_Float16)b.w;
        xh[i] = h;
    }
}

// ---------------------------------------------------------------------------
// MFMA GEMM, request-coalesced staging: C(Mx768) = A @ BT^T + bias.
// 128x128 tile, 4 waves, BK=64 (12 K-steps), LDS dbuf 2x32KB.
// KEY FIX vs rounds 1-6: staging decomposition is (row = t>>3, chunk = t&7)
// so each 8-lane group covers ONE aligned 128B segment -> 8 requests per
// global_load_lds instead of 64 scattered 16B requests (the measured
// request-path limiter: R5 75M req = 179us, R7 40M = 209us, R2 37M = 112us).
// Requests/dispatch: 4.7M @128B (8x fewer, 8x larger).
// LDS layout [row][chunk] with XOR swizzle (both-sides, rule #21):
//   store: linear dest; SOURCE chunk pre-swizzled kc^(row&7) (stays inside
//          the same 128B segment -> coalescing preserved)
//   read:  slot = (ki*4+q) ^ (m&7)  -> 2 lanes/bank = conflict-free.
// Schedule: R2-proven 2-phase counted-vmcnt dbuf (16 outstanding, wait 8).
// MODE 0: epilogue bias+rope (P). MODE 1: epilogue bias (Y).
// ---------------------------------------------------------------------------
template<int MODE>
__global__ __launch_bounds__(256, 2) void mfma_gemm(
    const _Float16* __restrict__ A,
    const _Float16* __restrict__ BT,
    const float* __restrict__ bias,
    const float* __restrict__ rope,
    float* __restrict__ C)
{
    const int t = threadIdx.x;
    const int lane = t & 63;
    const int wave = t >> 6;

    // XCD-aware swizzle of the 1536-block grid (6 x 256)
    const int flat = blockIdx.y * 6 + blockIdx.x;
    const int xcd = flat & 7;
    const int sub = flat >> 3;          // 0..191
    const int ct  = sub % 6;
    const int rt  = xcd * 32 + sub / 6; // 0..255
    const int row0 = rt * 128;
    const int col0 = ct * 128;

    const int wrow = (wave >> 1) * 64;
    const int wcol = (wave & 1) * 64;

    __shared__ v8h As[2][1024];   // [buf][row*8 + slot], 16KB per buf
    __shared__ v8h Bs[2][1024];

    v4f acc[4][4];
    #pragma unroll
    for (int i = 0; i < 4; ++i)
        #pragma unroll
        for (int j = 0; j < 4; ++j)
            acc[i][j] = (v4f){0.f, 0.f, 0.f, 0.f};

    const v8h* gA = (const v8h*)A;     // row stride 96 chunks
    const v8h* gB = (const v8h*)BT;

    // staging: thread t -> (local row = j*32 + (t>>3), chunk = t&7), j=0..3.
    // dest chunk index = j*256 + t (linear). Source chunk PRE-SWIZZLED:
    // kcs = (t&7) ^ (row&7); row&7 == (t>>3)&7 since j*32 % 8 == 0.
    const int srow = t >> 3;
    const int skc  = (t & 7) ^ (srow & 7);
    size_t gaJ[4], gbJ[4];
    #pragma unroll
    for (int j = 0; j < 4; ++j) {
        gaJ[j] = (size_t)(row0 + j*32 + srow)*96 + skc;
        gbJ[j] = (size_t)(col0 + j*32 + srow)*96 + skc;
    }

    const int q = lane >> 4;   // k-sub-chunk within fragment
    const int m = lane & 15;
    const int mx = m & 7;      // read-side XOR key

#define STAGE(b, ks) do {                                                      \
    _Pragma("unroll")                                                          \
    for (int j_ = 0; j_ < 4; ++j_)                                             \
        GLDS16((char*)&As[b][0] + j_*4096 + t*16, gA + gaJ[j_] + (ks)*8);      \
    _Pragma("unroll")                                                          \
    for (int j_ = 0; j_ < 4; ++j_)                                             \
        GLDS16((char*)&Bs[b][0] + j_*4096 + t*16, gB + gbJ[j_] + (ks)*8);      \
} while (0)

// Fragment element (row = wrow+mi*16+m, logical chunk = ki*4+q) lives at
// slot = (ki*4+q) ^ (row&7) = (ki*4+q) ^ mx  (wrow, mi*16 are 0 mod 8).
// Bank check per 16-lane phase: 8 distinct slots x 2 lanes = 2-way = free.
#define CMP(b) do {                                                            \
    _Pragma("unroll")                                                          \
    for (int ki_ = 0; ki_ < 2; ++ki_) {                                        \
        v8h af[4], bf[4];                                                      \
        _Pragma("unroll")                                                      \
        for (int i_ = 0; i_ < 4; ++i_)                                         \
            af[i_] = As[b][(wrow + i_*16 + m)*8 + ((ki_*4 + q) ^ mx)];         \
        _Pragma("unroll")                                                      \
        for (int i_ = 0; i_ < 4; ++i_)                                         \
            bf[i_] = Bs[b][(wcol + i_*16 + m)*8 + ((ki_*4 + q) ^ mx)];         \
        __builtin_amdgcn_s_setprio(1);                                         \
        _Pragma("unroll")                                                      \
        for (int mi_ = 0; mi_ < 4; ++mi_)                                      \
            _Pragma("unroll")                                                  \
            for (int ni_ = 0; ni_ < 4; ++ni_)                                  \
                acc[mi_][ni_] = __builtin_amdgcn_mfma_f32_16x16x32_f16(        \
                    af[mi_], bf[ni_], acc[mi_][ni_], 0, 0, 0);                 \
        __builtin_amdgcn_s_setprio(0);                                         \
    }                                                                          \
} while (0)

    // 12 K-tiles (BK=64 = 8 chunks), 2-phase dbuf, counted vmcnt (never 0
    // mid-loop): after STAGE there are 16 outstanding, wait to 8 = prev tile.
    STAGE(0, 0);
    for (int u = 0; u < 5; ++u) {
        STAGE(1, 2*u + 1); VMCNT(8); BAR(); CMP(0); BAR();
        STAGE(0, 2*u + 2); VMCNT(8); BAR(); CMP(1); BAR();
    }
    STAGE(1, 11); VMCNT(8); BAR(); CMP(0); BAR();
    VMCNT(0);               BAR(); CMP(1);

#undef STAGE
#undef CMP

    // Epilogue. C/D layout: col = lane&15, row = (lane>>4)*4 + reg.
    #pragma unroll
    for (int mi = 0; mi < 4; ++mi) {
        #pragma unroll
        for (int i = 0; i < 4; ++i) {
            const int grow = row0 + wrow + mi*16 + q*4 + i;
            #pragma unroll
            for (int ni = 0; ni < 4; ++ni) {
                const int gcol = col0 + wcol + ni*16 + m;
                float v = acc[mi][ni][i] + bias[gcol];
                if (MODE == 0) {
                    const int s = grow & 4095;
                    if (gcol >= 72 && gcol < 456)
                        v *= rope[s*64 + ((gcol - 72) & 63)];
                    else if (gcol >= 480 && gcol < 608)
                        v *= rope[s*64 + ((gcol - 480) & 63)];
                }
                C[(size_t)grow*768 + gcol] = v;
            }
        }
    }
}

// ---------------------------------------------------------------------------
// Factorized per-position attention (rope already in P). 8 positions per
// 256-thread block. O fp16, layout [b][h][s][d].
// ---------------------------------------------------------------------------
__global__ __launch_bounds__(256) void tpa_attn_f(
    const float* __restrict__ P,
    _Float16* __restrict__ O)
{
    const int t = threadIdx.x;
    const int pos0 = blockIdx.x * 8;

    __shared__ float proj[8][772];   // row pad 768->772: de-bank positions
    __shared__ float Gs[8][12];
    __shared__ float sc[8][160];     // 12 rows x stride 13
    __shared__ float cs[8][24];

    // load 8 P-rows (float4)
    const float4* gp = (const float4*)P;
    for (int i = t; i < 8*192; i += 256) {
        int p = i / 192, c = i - p*192;
        float4 u = gp[(size_t)(pos0 + p)*192 + c];
        proj[p][c*4+0] = u.x; proj[p][c*4+1] = u.y;
        proj[p][c*4+2] = u.z; proj[p][c*4+3] = u.w;
    }
    __syncthreads();

    // Gram matrix: 8 pos x 12 (r,r') pairs
    if (t < 96) {
        int p = t / 12, u = t - (t/12)*12, r = u >> 1, r2 = u & 1;
        const float* bq = &proj[p][72  + r*64];
        const float* bk = &proj[p][480 + r2*64];
        const int ph = (r*8 + r2*16) & 63;   // stagger start to spread banks
        float acc = 0.f;
        for (int i = 0; i < 64; ++i) {
            int d = (i + ph) & 63;
            acc = fmaf(bq[d], bk[d], acc);
        }
        Gs[p][u] = acc * 0.125f;
    }
    __syncthreads();

    // scores: 8 pos x 144 (h,g)
    for (int i = t; i < 8*144; i += 256) {
        int p = i / 144, v = i - p*144, h = v / 12, g = v - (v/12)*12;
        float s = 0.f;
        #pragma unroll
        for (int r = 0; r < RQ; ++r) {
            float mg = fmaf(Gs[p][r*2+1], proj[p][468 + g],
                            Gs[p][r*2+0] * proj[p][456 + g]);
            s = fmaf(proj[p][r*12 + h], mg, s);
        }
        sc[p][h*13 + g] = s;
    }
    __syncthreads();

    // softmax over g: 96 rows
    if (t < 96) {
        int p = t / 12, h = t - (t/12)*12;
        float* row = &sc[p][h*13];
        float mx = -1e30f;
        #pragma unroll
        for (int g = 0; g < NH; ++g) mx = fmaxf(mx, row[g]);
        float sum = 0.f;
        #pragma unroll
        for (int g = 0; g < NH; ++g) { float e = __expf(row[g]-mx); row[g] = e; sum += e; }
        float inv = 1.0f / sum;
        #pragma unroll
        for (int g = 0; g < NH; ++g) row[g] *= inv;
    }
    __syncthreads();

    // c[h,r'] = attn . av^T : 8 pos x 24
    if (t < 192) {
        int p = t / 24, u = t - (t/24)*24, h = u >> 1, r2 = u & 1;
        float acc = 0.f;
        #pragma unroll
        for (int g = 0; g < NH; ++g)
            acc = fmaf(sc[p][h*13+g], proj[p][608 + r2*12 + g], acc);
        cs[p][h*2 + r2] = acc;
    }
    __syncthreads();

    // out: 8 pos x 768, d fastest for coalesced fp16 stores
    for (int i = t; i < 8*768; i += 256) {
        int p = i / 768, j = i - p*768, h = j >> 6, d = j & 63;
        int pos = pos0 + p, b = pos >> 12, s = pos & 4095;
        float val = fmaf(cs[p][h*2+1], proj[p][632 + 64 + d],
                         cs[p][h*2+0] * proj[p][632 + d]);
        O[(((size_t)b*NH + h)*SEQ + s)*DK + d] = (_Float16)val;
    }
}

extern "C" void kernel_launch(void* const* d_in, const int* in_sizes, int n_in,
                              void* d_out, int out_size, void* d_ws, size_t ws_size,
                              hipStream_t stream) {
    const float* x    = (const float*)d_in[0];
    const float* rope = (const float*)d_in[1];
    const float* Waq  = (const float*)d_in[2];
    const float* baq  = (const float*)d_in[3];
    const float* Wbq  = (const float*)d_in[4];
    const float* bbq  = (const float*)d_in[5];
    const float* Wak  = (const float*)d_in[6];
    const float* bak  = (const float*)d_in[7];
    const float* Wbk  = (const float*)d_in[8];
    const float* bbk  = (const float*)d_in[9];
    const float* Wav  = (const float*)d_in[10];
    const float* bav  = (const float*)d_in[11];
    const float* Wbv  = (const float*)d_in[12];
    const float* bbv  = (const float*)d_in[13];
    const float* Wo   = (const float*)d_in[14];
    const float* bo   = (const float*)d_in[15];

    // ws layout (total ~52.7 MB): fp16 weights + fp16 O
    char* ws = (char*)d_ws;
    _Float16* WcatT = (_Float16*)(ws);                 // 1,179,648 B
    _Float16* WoT   = (_Float16*)(ws + 1179648);       // 1,179,648 B
    float*    bcat  = (float*)(ws + 2359296);          // 3,072 B
    _Float16* O     = (_Float16*)(ws + 2363392);       // 50,331,648 B

    // P (fp32, 32768x768) lives in d_out; fully consumed by tpa_attn_f
    // before the final GEMM overwrites d_out.
    float* P = (float*)d_out;

    // Xh (fp16 x, 48 MB) time-shares the O region.
    _Float16* Xh = O;

    repack<<<768, 256, 0, stream>>>(Waq, baq, Wbq, bbq, Wak, bak, Wbk, bbk,
                                    Wav, bav, Wbv, bbv, Wo, WcatT, WoT, bcat);

    convert_x<<<1024, 256, 0, stream>>>((const float4*)x, (v8h*)Xh);

    dim3 gg(6, 256);
    mfma_gemm<0><<<gg, 256, 0, stream>>>(Xh, WcatT, bcat, rope, P);

    tpa_attn_f<<<NPOS/8, 256, 0, stream>>>(P, O);

    mfma_gemm<1><<<gg, 256, 0, stream>>>(O, WoT, bo, nullptr, (float*)d_out);
}